// Round 7
// baseline (44.525 us; speedup 1.0000x reference)
//
#include <hip/hip_runtime.h>

typedef float f32x4 __attribute__((ext_vector_type(4)));
typedef short s16x8 __attribute__((ext_vector_type(8)));
typedef unsigned int u32;
typedef unsigned int u32x4 __attribute__((ext_vector_type(4)));
typedef unsigned short u16;

#define DIN 24
#define DH1 64
#define DH2 128
#define DOUT 64
#define OROW 272   // out-tile LDS row stride in bytes (256 data + 16 pad)

// f32 -> bf16 bits, RNE (setup path)
static __device__ __forceinline__ u16 f2bf(float f) {
    u32 u = __builtin_bit_cast(u32, f);
    u += 0x7FFFu + ((u >> 16) & 1u);
    return (u16)(u >> 16);
}
// packed f32x2 -> bf16x2, one VALU op
static __device__ __forceinline__ u32 cvtpk(float lo, float hi) {
    u32 r;
    asm("v_cvt_pk_bf16_f32 %0, %1, %2" : "=v"(r) : "v"(lo), "v"(hi));
    return r;
}
static __device__ __forceinline__ float bflo(u32 pk) {
    return __builtin_bit_cast(float, pk << 16);
}
static __device__ __forceinline__ float bfhi(u32 pk) {
    return __builtin_bit_cast(float, pk & 0xFFFF0000u);
}
// cross-lane chunk-transpose primitives (bit-exactness HW-verified in R4)
static __device__ __forceinline__ void swap32(u32& a, u32& b) {
    asm("v_permlane32_swap_b32 %0, %1" : "+v"(a), "+v"(b));
}
static __device__ __forceinline__ void swap16(u32& a, u32& b) {
    asm("v_permlane16_swap_b32 %0, %1" : "+v"(a), "+v"(b));
}

__global__ __launch_bounds__(256, 2) void linenet_r7(
    const float* __restrict__ in,
    const float* __restrict__ W1, const float* __restrict__ b1,
    const float* __restrict__ W2, const float* __restrict__ b2,
    const float* __restrict__ W3, const float* __restrict__ b3,
    float* __restrict__ out, int M)
{
    // wave-private out-tile staging for store coalescing (16 rows x 272 B)
    __shared__ __align__(16) char olds[4][16 * OROW];

    const int tid  = threadIdx.x;
    const int lane = tid & 63;
    const int gl = lane >> 4, cl = lane & 15;

    // ---- ALL weights VGPR-resident (R6 structure) ----
    s16x8 w1tf[4];                       // W1^T [64x32], k=24 row = b1 bias
    #pragma unroll
    for (int nt = 0; nt < 4; ++nt)
        #pragma unroll
        for (int j = 0; j < 8; ++j) {
            const int k = 8 * gl + j;
            u16 x = 0;
            if (k < DIN)       x = f2bf(W1[k * DH1 + nt * 16 + cl]);
            else if (k == DIN) x = f2bf(b1[nt * 16 + cl]);
            w1tf[nt][j] = (short)x;
        }
    s16x8 w2tf[8][2];                    // W2^T [128x64]
    #pragma unroll
    for (int mt = 0; mt < 8; ++mt)
        #pragma unroll
        for (int ks = 0; ks < 2; ++ks)
            #pragma unroll
            for (int j = 0; j < 8; ++j)
                w2tf[mt][ks][j] =
                    (short)f2bf(W2[(32 * ks + 8 * gl + j) * DH2 + mt * 16 + cl]);
    s16x8 w3tf[4][4];                    // W3^T [64x128]
    #pragma unroll
    for (int nt = 0; nt < 4; ++nt)
        #pragma unroll
        for (int ks = 0; ks < 4; ++ks)
            #pragma unroll
            for (int j = 0; j < 8; ++j)
                w3tf[nt][ks][j] =
                    (short)f2bf(W3[(32 * ks + 8 * gl + j) * DOUT + nt * 16 + cl]);

    // biases packed bf16x2 (per-lane features 16t+4gl+{0..3})
    u32 b2pk[8][2], b3pk[4][2];
    #pragma unroll
    for (int mt = 0; mt < 8; ++mt)
        #pragma unroll
        for (int p = 0; p < 2; ++p)
            b2pk[mt][p] = (u32)f2bf(b2[16 * mt + 4 * gl + 2 * p]) |
                          ((u32)f2bf(b2[16 * mt + 4 * gl + 2 * p + 1]) << 16);
    #pragma unroll
    for (int nt = 0; nt < 4; ++nt)
        #pragma unroll
        for (int p = 0; p < 2; ++p)
            b3pk[nt][p] = (u32)f2bf(b3[16 * nt + 4 * gl + 2 * p]) |
                          ((u32)f2bf(b3[16 * nt + 4 * gl + 2 * p + 1]) << 16);

    const int NT = M / 16;
    const int nw = (int)gridDim.x * 4;
    int t = (int)blockIdx.x * 4 + (tid >> 6);
    if (t >= NT) return;

    char* const ot = &olds[tid >> 6][0];

    // x^T B-frag source: lane (gl,cl) = row cl, 8 floats at 8*gl (gl<3);
    // gl==3: k=24 slot forced to 1.0 (bias row), k=25..31 hit zero weights.
    const int goff = (gl < 3) ? 8 * gl : 0;
    const int loff = cl * DIN + goff;

    f32x4 pf0, pf1;
    {
        const float* p = in + (size_t)t * (16 * DIN) + loff;
        pf0 = *(const f32x4*)p;
        pf1 = *(const f32x4*)(p + 4);
    }

    const f32x4 zac = {0.f, 0.f, 0.f, 0.f};

    while (t < NT) {
        // ---- x^T fragment ----
        u32x4 aw;
        aw[0] = cvtpk(pf0[0], pf0[1]);
        aw[1] = cvtpk(pf0[2], pf0[3]);
        aw[2] = cvtpk(pf1[0], pf1[1]);
        aw[3] = cvtpk(pf1[2], pf1[3]);
        if (gl == 3) aw[0] = 0x00003F80u;   // k=24 -> 1.0, k=25 -> 0
        const s16x8 a1 = __builtin_bit_cast(s16x8, aw);

        // ---- prefetch next tile (depth-1) ----
        const int tn = t + nw;
        {
            const int tc = (tn < NT) ? tn : t;
            const float* p = in + (size_t)tc * (16 * DIN) + loff;
            pf0 = *(const f32x4*)p;
            pf1 = *(const f32x4*)(p + 4);
        }

        // ---- layer 1: h1^T = W1^T(+b1 row) * x^T ----
        f32x4 acc1[4];
        #pragma unroll
        for (int nt = 0; nt < 4; ++nt)
            acc1[nt] = __builtin_amdgcn_mfma_f32_16x16x32_bf16(w1tf[nt], a1, zac, 0, 0, 0);

        // relu + pack + in-register transpose
        u32 cw[4][2];
        #pragma unroll
        for (int nt = 0; nt < 4; ++nt) {
            cw[nt][0] = cvtpk(fmaxf(acc1[nt][0], 0.f), fmaxf(acc1[nt][1], 0.f));
            cw[nt][1] = cvtpk(fmaxf(acc1[nt][2], 0.f), fmaxf(acc1[nt][3], 0.f));
        }
        swap32(cw[0][0], cw[1][0]); swap32(cw[0][1], cw[1][1]);
        swap32(cw[2][0], cw[3][0]); swap32(cw[2][1], cw[3][1]);
        swap16(cw[0][0], cw[1][0]); swap16(cw[0][1], cw[1][1]);
        swap16(cw[2][0], cw[3][0]); swap16(cw[2][1], cw[3][1]);
        s16x8 bh1[2];
        {
            u32x4 q0 = {cw[0][0], cw[0][1], cw[1][0], cw[1][1]};
            u32x4 q1 = {cw[2][0], cw[2][1], cw[3][0], cw[3][1]};
            bh1[0] = __builtin_bit_cast(s16x8, q0);
            bh1[1] = __builtin_bit_cast(s16x8, q1);
        }

        // ---- layer 2: h2^T = W2^T * h1^T + b2 (bias as C-operand) ----
        u32 cw2[8][2];
        #pragma unroll
        for (int mt = 0; mt < 8; ++mt) {
            f32x4 c2;
            c2[0] = bflo(b2pk[mt][0]); c2[1] = bfhi(b2pk[mt][0]);
            c2[2] = bflo(b2pk[mt][1]); c2[3] = bfhi(b2pk[mt][1]);
            f32x4 acc2 = __builtin_amdgcn_mfma_f32_16x16x32_bf16(w2tf[mt][0], bh1[0], c2, 0, 0, 0);
            acc2 = __builtin_amdgcn_mfma_f32_16x16x32_bf16(w2tf[mt][1], bh1[1], acc2, 0, 0, 0);
            cw2[mt][0] = cvtpk(fmaxf(acc2[0], 0.f), fmaxf(acc2[1], 0.f));
            cw2[mt][1] = cvtpk(fmaxf(acc2[2], 0.f), fmaxf(acc2[3], 0.f));
        }
        #pragma unroll
        for (int m = 0; m < 8; m += 2) {
            swap32(cw2[m][0], cw2[m + 1][0]);
            swap32(cw2[m][1], cw2[m + 1][1]);
        }
        #pragma unroll
        for (int m = 0; m < 8; m += 2) {
            swap16(cw2[m][0], cw2[m + 1][0]);
            swap16(cw2[m][1], cw2[m + 1][1]);
        }
        s16x8 bh2[4];
        #pragma unroll
        for (int ks = 0; ks < 4; ++ks) {
            u32x4 q = {cw2[2 * ks][0], cw2[2 * ks][1],
                       cw2[2 * ks + 1][0], cw2[2 * ks + 1][1]};
            bh2[ks] = __builtin_bit_cast(s16x8, q);
        }

        // ---- layer 3: out^T = W3^T * h2^T + b3 (bias as C-init) ----
        f32x4 acc3[4];
        #pragma unroll
        for (int nt = 0; nt < 4; ++nt) {
            acc3[nt][0] = bflo(b3pk[nt][0]); acc3[nt][1] = bfhi(b3pk[nt][0]);
            acc3[nt][2] = bflo(b3pk[nt][1]); acc3[nt][3] = bfhi(b3pk[nt][1]);
        }
        #pragma unroll
        for (int ks = 0; ks < 4; ++ks)
            #pragma unroll
            for (int nt = 0; nt < 4; ++nt)
                acc3[nt] = __builtin_amdgcn_mfma_f32_16x16x32_bf16(
                    w3tf[nt][ks], bh2[ks], acc3[nt], 0, 0, 0);

        // ---- epilogue: relu -> wave-private LDS -> fully-contiguous stores ----
        // write: lane(gl,cl) has out[row=cl][feat=16nt+4gl..+3]
        #pragma unroll
        for (int nt = 0; nt < 4; ++nt) {
            f32x4 v;
            v[0] = fmaxf(acc3[nt][0], 0.f); v[1] = fmaxf(acc3[nt][1], 0.f);
            v[2] = fmaxf(acc3[nt][2], 0.f); v[3] = fmaxf(acc3[nt][3], 0.f);
            *(f32x4*)(ot + cl * OROW + nt * 64 + gl * 16) = v;
        }
        // read linear image; store 1024 B contiguous per instruction
        float* const ob = out + (size_t)t * (16 * DOUT);
        #pragma unroll
        for (int i = 0; i < 4; ++i) {
            const f32x4 v = *(const f32x4*)(ot + (4 * i + gl) * OROW + cl * 16);
            *(f32x4*)&ob[i * 256 + lane * 4] = v;
        }

        t = tn;
    }
}

extern "C" void kernel_launch(void* const* d_in, const int* in_sizes, int n_in,
                              void* d_out, int out_size, void* d_ws, size_t ws_size,
                              hipStream_t stream)
{
    const float* in = (const float*)d_in[0];
    const float* W1 = (const float*)d_in[1];
    const float* b1 = (const float*)d_in[2];
    const float* W2 = (const float*)d_in[3];
    const float* b2 = (const float*)d_in[4];
    const float* W3 = (const float*)d_in[5];
    const float* b3 = (const float*)d_in[6];
    float* out = (float*)d_out;
    const int M = in_sizes[0] / DIN;

    dim3 grid(512), block(256);   // 2 blocks/CU, all-VGPR weights, 17.4KB LDS
    hipLaunchKernelGGL(linenet_r7, grid, block, 0, stream,
                       in, W1, b1, W2, b2, W3, b3, out, M);
}

// Round 8
// 40.225 us; speedup vs baseline: 1.1069x; 1.1069x over previous
//
#include <hip/hip_runtime.h>

typedef float f32x4 __attribute__((ext_vector_type(4)));
typedef short s16x8 __attribute__((ext_vector_type(8)));
typedef unsigned int u32;
typedef unsigned int u32x4 __attribute__((ext_vector_type(4)));
typedef unsigned short u16;

#define DIN 24
#define DH1 64
#define DH2 128
#define DOUT 64

// f32 -> bf16 bits, RNE (setup path)
static __device__ __forceinline__ u16 f2bf(float f) {
    u32 u = __builtin_bit_cast(u32, f);
    u += 0x7FFFu + ((u >> 16) & 1u);
    return (u16)(u >> 16);
}
// packed f32x2 -> bf16x2, one VALU op
static __device__ __forceinline__ u32 cvtpk(float lo, float hi) {
    u32 r;
    asm("v_cvt_pk_bf16_f32 %0, %1, %2" : "=v"(r) : "v"(lo), "v"(hi));
    return r;
}
static __device__ __forceinline__ float bflo(u32 pk) {
    return __builtin_bit_cast(float, pk << 16);
}
static __device__ __forceinline__ float bfhi(u32 pk) {
    return __builtin_bit_cast(float, pk & 0xFFFF0000u);
}
// cross-lane chunk-transpose primitives (bit-exactness HW-verified in R4)
static __device__ __forceinline__ void swap32(u32& a, u32& b) {
    asm("v_permlane32_swap_b32 %0, %1" : "+v"(a), "+v"(b));
}
static __device__ __forceinline__ void swap16(u32& a, u32& b) {
    asm("v_permlane16_swap_b32 %0, %1" : "+v"(a), "+v"(b));
}

__global__ __launch_bounds__(256, 3) void linenet_r8(
    const float* __restrict__ in,
    const float* __restrict__ W1, const float* __restrict__ b1,
    const float* __restrict__ W2, const float* __restrict__ b2,
    const float* __restrict__ W3, const float* __restrict__ b3,
    float* __restrict__ out, int M)
{
    // ALL weight fragment tables in LDS (36KB/block, shared by 4 waves).
    // Frees ~104 VGPR/lane -> 3 waves/EU without spills. Reads are
    // lane-contiguous 16B (1KB/frag/wave) -> 2-way bank aliasing = free.
    __shared__ __align__(16) u16 w1lds[4 * 64 * 8];    // 4KB  (k=24 row = b1)
    __shared__ __align__(16) u16 w2lds[16 * 64 * 8];   // 16KB (frag = mt*2+ks)
    __shared__ __align__(16) u16 w3lds[16 * 64 * 8];   // 16KB (frag = ks*4+nt)

    const int tid  = threadIdx.x;
    const int lane = tid & 63;
    const int gl = lane >> 4, cl = lane & 15;

    // ---- build W1^T table: one entry per thread ----
    {
        const int nt = tid >> 6, ln = tid & 63;
        const int g = ln >> 4, c = ln & 15;
        s16x8 v;
        #pragma unroll
        for (int j = 0; j < 8; ++j) {
            const int k = 8 * g + j;
            u16 x = 0;
            if (k < DIN)       x = f2bf(W1[k * DH1 + nt * 16 + c]);
            else if (k == DIN) x = f2bf(b1[nt * 16 + c]);
            v[j] = (short)x;
        }
        *(s16x8*)&w1lds[tid * 8] = v;
    }
    // ---- build W2^T table (frag index = mt*2+ks) ----
    for (int it = tid; it < 16 * 64; it += 256) {
        const int f = it >> 6, ln = it & 63;
        const int mt = f >> 1, ks = f & 1, g = ln >> 4, c = ln & 15;
        s16x8 v;
        #pragma unroll
        for (int j = 0; j < 8; ++j)
            v[j] = (short)f2bf(W2[(32 * ks + 8 * g + j) * DH2 + mt * 16 + c]);
        *(s16x8*)&w2lds[it * 8] = v;
    }
    // ---- build W3^T table (frag index = ks*4+nt) ----
    for (int it = tid; it < 16 * 64; it += 256) {
        const int f = it >> 6, ln = it & 63;
        const int ks = f >> 2, nt = f & 3, g = ln >> 4, c = ln & 15;
        s16x8 v;
        #pragma unroll
        for (int j = 0; j < 8; ++j)
            v[j] = (short)f2bf(W3[(32 * ks + 8 * g + j) * DOUT + nt * 16 + c]);
        *(s16x8*)&w3lds[it * 8] = v;
    }

    // ---- biases packed bf16x2 in VGPR (24 regs; per-lane features 16t+4gl+{0..3}) ----
    u32 b2pk[8][2], b3pk[4][2];
    #pragma unroll
    for (int mt = 0; mt < 8; ++mt)
        #pragma unroll
        for (int p = 0; p < 2; ++p)
            b2pk[mt][p] = (u32)f2bf(b2[16 * mt + 4 * gl + 2 * p]) |
                          ((u32)f2bf(b2[16 * mt + 4 * gl + 2 * p + 1]) << 16);
    #pragma unroll
    for (int nt = 0; nt < 4; ++nt)
        #pragma unroll
        for (int p = 0; p < 2; ++p)
            b3pk[nt][p] = (u32)f2bf(b3[16 * nt + 4 * gl + 2 * p]) |
                          ((u32)f2bf(b3[16 * nt + 4 * gl + 2 * p + 1]) << 16);

    __syncthreads();

    const int NT = M / 16;
    const int nw = (int)gridDim.x * 4;
    int t = (int)blockIdx.x * 4 + (tid >> 6);
    if (t >= NT) return;

    // x^T B-frag source: lane (gl,cl) = row cl, 8 floats at 8*gl (gl<3);
    // gl==3: k=24 slot forced to 1.0 (bias row), k=25..31 hit zero weights.
    const int goff = (gl < 3) ? 8 * gl : 0;
    const int loff = cl * DIN + goff;

    f32x4 pf0, pf1;
    {
        const float* p = in + (size_t)t * (16 * DIN) + loff;
        pf0 = *(const f32x4*)p;
        pf1 = *(const f32x4*)(p + 4);
    }

    const f32x4 zac = {0.f, 0.f, 0.f, 0.f};

    while (t < NT) {
        // ---- x^T fragment ----
        u32x4 aw;
        aw[0] = cvtpk(pf0[0], pf0[1]);
        aw[1] = cvtpk(pf0[2], pf0[3]);
        aw[2] = cvtpk(pf1[0], pf1[1]);
        aw[3] = cvtpk(pf1[2], pf1[3]);
        if (gl == 3) aw[0] = 0x00003F80u;   // k=24 -> 1.0, k=25 -> 0
        const s16x8 a1 = __builtin_bit_cast(s16x8, aw);

        // ---- prefetch next tile (depth-1) ----
        const int tn = t + nw;
        {
            const int tc = (tn < NT) ? tn : t;
            const float* p = in + (size_t)tc * (16 * DIN) + loff;
            pf0 = *(const f32x4*)p;
            pf1 = *(const f32x4*)(p + 4);
        }

        // ---- layer 1: h1^T = W1^T(+b1 row) * x^T ----
        f32x4 acc1[4];
        #pragma unroll
        for (int nt = 0; nt < 4; ++nt) {
            const s16x8 w1f = *(const s16x8*)&w1lds[(nt * 64 + lane) * 8];
            acc1[nt] = __builtin_amdgcn_mfma_f32_16x16x32_bf16(w1f, a1, zac, 0, 0, 0);
        }

        // relu + pack + in-register transpose
        u32 cw[4][2];
        #pragma unroll
        for (int nt = 0; nt < 4; ++nt) {
            cw[nt][0] = cvtpk(fmaxf(acc1[nt][0], 0.f), fmaxf(acc1[nt][1], 0.f));
            cw[nt][1] = cvtpk(fmaxf(acc1[nt][2], 0.f), fmaxf(acc1[nt][3], 0.f));
        }
        swap32(cw[0][0], cw[1][0]); swap32(cw[0][1], cw[1][1]);
        swap32(cw[2][0], cw[3][0]); swap32(cw[2][1], cw[3][1]);
        swap16(cw[0][0], cw[1][0]); swap16(cw[0][1], cw[1][1]);
        swap16(cw[2][0], cw[3][0]); swap16(cw[2][1], cw[3][1]);
        s16x8 bh1[2];
        {
            u32x4 q0 = {cw[0][0], cw[0][1], cw[1][0], cw[1][1]};
            u32x4 q1 = {cw[2][0], cw[2][1], cw[3][0], cw[3][1]};
            bh1[0] = __builtin_bit_cast(s16x8, q0);
            bh1[1] = __builtin_bit_cast(s16x8, q1);
        }

        // ---- layer 2: h2^T = W2^T * h1^T + b2 (bias as C-operand) ----
        u32 cw2[8][2];
        #pragma unroll
        for (int mt = 0; mt < 8; ++mt) {
            f32x4 c2;
            c2[0] = bflo(b2pk[mt][0]); c2[1] = bfhi(b2pk[mt][0]);
            c2[2] = bflo(b2pk[mt][1]); c2[3] = bfhi(b2pk[mt][1]);
            const s16x8 w2a = *(const s16x8*)&w2lds[((mt * 2 + 0) * 64 + lane) * 8];
            const s16x8 w2b = *(const s16x8*)&w2lds[((mt * 2 + 1) * 64 + lane) * 8];
            f32x4 acc2 = __builtin_amdgcn_mfma_f32_16x16x32_bf16(w2a, bh1[0], c2, 0, 0, 0);
            acc2 = __builtin_amdgcn_mfma_f32_16x16x32_bf16(w2b, bh1[1], acc2, 0, 0, 0);
            cw2[mt][0] = cvtpk(fmaxf(acc2[0], 0.f), fmaxf(acc2[1], 0.f));
            cw2[mt][1] = cvtpk(fmaxf(acc2[2], 0.f), fmaxf(acc2[3], 0.f));
        }
        #pragma unroll
        for (int m = 0; m < 8; m += 2) {
            swap32(cw2[m][0], cw2[m + 1][0]);
            swap32(cw2[m][1], cw2[m + 1][1]);
        }
        #pragma unroll
        for (int m = 0; m < 8; m += 2) {
            swap16(cw2[m][0], cw2[m + 1][0]);
            swap16(cw2[m][1], cw2[m + 1][1]);
        }
        s16x8 bh2[4];
        #pragma unroll
        for (int ks = 0; ks < 4; ++ks) {
            u32x4 q = {cw2[2 * ks][0], cw2[2 * ks][1],
                       cw2[2 * ks + 1][0], cw2[2 * ks + 1][1]};
            bh2[ks] = __builtin_bit_cast(s16x8, q);
        }

        // ---- layer 3: out^T = W3^T * h2^T + b3 (bias as C-init) ----
        f32x4 acc3[4];
        #pragma unroll
        for (int nt = 0; nt < 4; ++nt) {
            acc3[nt][0] = bflo(b3pk[nt][0]); acc3[nt][1] = bfhi(b3pk[nt][0]);
            acc3[nt][2] = bflo(b3pk[nt][1]); acc3[nt][3] = bfhi(b3pk[nt][1]);
        }
        #pragma unroll
        for (int ks = 0; ks < 4; ++ks) {
            #pragma unroll
            for (int nt = 0; nt < 4; ++nt) {
                const s16x8 wf = *(const s16x8*)&w3lds[((ks * 4 + nt) * 64 + lane) * 8];
                acc3[nt] = __builtin_amdgcn_mfma_f32_16x16x32_bf16(
                    wf, bh2[ks], acc3[nt], 0, 0, 0);
            }
        }

        // ---- epilogue: relu + coalesced f32x4 stores ----
        float* const ob = out + (size_t)t * (16 * DOUT) + (size_t)cl * DOUT;
        #pragma unroll
        for (int nt = 0; nt < 4; ++nt) {
            f32x4 v;
            v[0] = fmaxf(acc3[nt][0], 0.f); v[1] = fmaxf(acc3[nt][1], 0.f);
            v[2] = fmaxf(acc3[nt][2], 0.f); v[3] = fmaxf(acc3[nt][3], 0.f);
            *(f32x4*)&ob[16 * nt + 4 * gl] = v;
        }

        t = tn;
    }
}

extern "C" void kernel_launch(void* const* d_in, const int* in_sizes, int n_in,
                              void* d_out, int out_size, void* d_ws, size_t ws_size,
                              hipStream_t stream)
{
    const float* in = (const float*)d_in[0];
    const float* W1 = (const float*)d_in[1];
    const float* b1 = (const float*)d_in[2];
    const float* W2 = (const float*)d_in[3];
    const float* b2 = (const float*)d_in[4];
    const float* W3 = (const float*)d_in[5];
    const float* b3 = (const float*)d_in[6];
    float* out = (float*)d_out;
    const int M = in_sizes[0] / DIN;

    dim3 grid(768), block(256);   // 3 blocks/CU (36KB LDS, VGPR ~125 <= 170) = 12 waves/CU
    hipLaunchKernelGGL(linenet_r8, grid, block, 0, stream,
                       in, W1, b1, W2, b2, W3, b3, out, M);
}